// Round 1
// baseline (653.456 us; speedup 1.0000x reference)
//
#include <hip/hip_runtime.h>
#include <hip/hip_bf16.h>

#define N_NODES 8192
#define N_EDGES 32768
#define DFEAT   512

typedef __attribute__((ext_vector_type(8))) short          bf16x8;
typedef __attribute__((ext_vector_type(4))) float          f32x4;
typedef __attribute__((ext_vector_type(8))) unsigned short u16x8;

__device__ __forceinline__ float bf2f(unsigned short u) {
  union { unsigned int i; float f; } x; x.i = ((unsigned int)u) << 16; return x.f;
}
__device__ __forceinline__ unsigned short f2bf(float f) {
  __hip_bfloat16 h = __float2bfloat16(f);
  return *reinterpret_cast<unsigned short*>(&h);
}

#define GLDS16(gp, lp) __builtin_amdgcn_global_load_lds( \
    (const __attribute__((address_space(1))) void*)(gp),  \
    (__attribute__((address_space(3))) void*)(lp), 16, 0, 0)

// ---------------- weight transpose fp32[K][512] -> bf16[512][K] ----------------
__global__ void transpose_w(const float* __restrict__ W, unsigned short* __restrict__ WT, int K) {
  __shared__ float tile[32][33];
  const int k0 = blockIdx.x * 32, n0 = blockIdx.y * 32;
  const int tx = threadIdx.x, ty = threadIdx.y;
  #pragma unroll
  for (int i = ty; i < 32; i += 8)
    tile[i][tx] = W[(long)(k0 + i) * DFEAT + n0 + tx];
  __syncthreads();
  #pragma unroll
  for (int i = ty; i < 32; i += 8)
    WT[(long)(n0 + i) * K + k0 + tx] = f2bf(tile[tx][i]);
}

// ---------------- fp32 -> bf16 flat convert ----------------
__global__ void cvt_f32_bf16(const float* __restrict__ src, unsigned short* __restrict__ dst, long n) {
  long i = ((long)blockIdx.x * blockDim.x + threadIdx.x) * 4;
  if (i >= n) return;
  float4 v = *reinterpret_cast<const float4*>(&src[i]);
  ushort4 o = { f2bf(v.x), f2bf(v.y), f2bf(v.z), f2bf(v.w) };
  *reinterpret_cast<ushort4*>(&dst[i]) = o;
}

// ---------------- gather helper: accumulate W rows (batched loads for MLP) ----------------
template<int W>
__device__ __forceinline__ void gather_acc(const unsigned short* __restrict__ base,
                                           const int* __restrict__ idxp, int c0,
                                           float* s, int& cnt) {
  int idx[W];
  u16x8 v[W];
  #pragma unroll
  for (int j = 0; j < W; ++j) idx[j] = idxp[j];
  #pragma unroll
  for (int j = 0; j < W; ++j) {
    int a = idx[j] >= 0 ? idx[j] : 0;
    v[j] = *reinterpret_cast<const u16x8*>(&base[(long)a * DFEAT + c0]);
  }
  #pragma unroll
  for (int j = 0; j < W; ++j) {
    if (idx[j] >= 0) {
      ++cnt;
      #pragma unroll
      for (int i = 0; i < 8; ++i) s[i] += bf2f(v[j][i]);
    }
  }
}

// ---------------- neighbor mean: (sum nodes[adj] + sum edges[eid]) / (c1+c2) ----------------
__global__ __launch_bounds__(256) void nbr_mean_kernel(
    const unsigned short* __restrict__ nodes, const unsigned short* __restrict__ edges,
    const int* __restrict__ adj, const int* __restrict__ eid,
    unsigned short* __restrict__ dst, int Nn) {
  const int wave = threadIdx.x >> 6, lane = threadIdx.x & 63;
  const int n = blockIdx.x * 4 + wave;
  if (n >= Nn) return;
  const int c0 = lane * 8;
  float s[8] = {0, 0, 0, 0, 0, 0, 0, 0};
  int cnt = 0;
  gather_acc<8>(nodes, adj + (long)n * 16, c0, s, cnt);
  gather_acc<8>(nodes, adj + (long)n * 16 + 8, c0, s, cnt);
  gather_acc<8>(edges, eid + (long)n * 16, c0, s, cnt);
  gather_acc<8>(edges, eid + (long)n * 16 + 8, c0, s, cnt);
  const float inv = 1.0f / (float)cnt;
  u16x8 o;
  #pragma unroll
  for (int i = 0; i < 8; ++i) o[i] = f2bf(s[i] * inv);
  *reinterpret_cast<u16x8*>(&dst[(long)n * DFEAT + c0]) = o;
}

// ---------------- edge dep means: fdep and bdep for each edge ----------------
__global__ __launch_bounds__(256) void edge_dep_kernel(
    const unsigned short* __restrict__ fw, const unsigned short* __restrict__ bw,
    const int* __restrict__ fdep, const int* __restrict__ bdep,
    unsigned short* __restrict__ Df, unsigned short* __restrict__ Db, int Ne) {
  const int wave = threadIdx.x >> 6, lane = threadIdx.x & 63;
  const int e = blockIdx.x * 4 + wave;
  if (e >= Ne) return;
  const int c0 = lane * 8;
  {
    float s[8] = {0, 0, 0, 0, 0, 0, 0, 0};
    int cnt = 0;
    gather_acc<8>(fw, fdep + (long)e * 8, c0, s, cnt);
    const float inv = 1.0f / (float)cnt;
    u16x8 o;
    #pragma unroll
    for (int i = 0; i < 8; ++i) o[i] = f2bf(s[i] * inv);
    *reinterpret_cast<u16x8*>(&Df[(long)e * DFEAT + c0]) = o;
  }
  {
    float s[8] = {0, 0, 0, 0, 0, 0, 0, 0};
    int cnt = 0;
    gather_acc<8>(bw, bdep + (long)e * 8, c0, s, cnt);
    const float inv = 1.0f / (float)cnt;
    u16x8 o;
    #pragma unroll
    for (int i = 0; i < 8; ++i) o[i] = f2bf(s[i] * inv);
    *reinterpret_cast<u16x8*>(&Db[(long)e * DFEAT + c0]) = o;
  }
}

// ---------------- GEMM: C[M,512] = concat(A0,A1[,A2]) @ Bt^T + bias ----------------
// A segments: bf16 [M][512] row-major. Bt: bf16 [512][K] row-major (pre-transposed weights).
// m97 structure: 128x128 tile, BK=32, 4 waves of 64x64, global_load_lds staging.
template<int NSEG, bool RELU, bool BF16OUT>
__global__ __launch_bounds__(256, 2) void gemm_seg(
    const unsigned short* __restrict__ A0, const unsigned short* __restrict__ A1,
    const unsigned short* __restrict__ A2, const unsigned short* __restrict__ Bt,
    const float* __restrict__ bias, unsigned short* __restrict__ outb,
    float* __restrict__ outf) {
  constexpr int K = NSEG * 512;
  __shared__ unsigned short As[128][32];
  __shared__ unsigned short Bs[128][32];
  const int tid = threadIdx.x;
  const int wave = tid >> 6, lane = tid & 63;
  const long brow = (long)blockIdx.x * 128;
  const int bcol = blockIdx.y * 128;
  const int wr = (wave >> 1) * 64, wc = (wave & 1) * 64;

  f32x4 acc[4][4] = {};

  const int srow = lane >> 2;         // 0..15
  const int scol = (lane & 3) * 8;    // 0,8,16,24
  const int rb = wave * 32;           // rows this wave stages
  unsigned short* As0 = &As[rb][0];
  unsigned short* As1 = &As[rb + 16][0];
  unsigned short* Bs0 = &Bs[rb][0];
  unsigned short* Bs1 = &Bs[rb + 16][0];

  const int fr = lane & 15;
  const int fk = (lane >> 4) * 8;

  for (int kt = 0; kt < K / 32; ++kt) {
    const unsigned short* Aseg;
    if (NSEG == 1) {
      Aseg = A0;
    } else {
      const int seg = kt >> 4;
      Aseg = (seg == 0) ? A0 : ((seg == 1) ? A1 : A2);
    }
    const int kcol = (kt & 15) * 32;
    GLDS16(Aseg + (brow + rb + srow) * DFEAT + kcol + scol, As0);
    GLDS16(Aseg + (brow + rb + 16 + srow) * DFEAT + kcol + scol, As1);
    const long bk = (long)kt * 32;
    GLDS16(Bt + (long)(bcol + rb + srow) * K + bk + scol, Bs0);
    GLDS16(Bt + (long)(bcol + rb + 16 + srow) * K + bk + scol, Bs1);
    __syncthreads();
    bf16x8 af[4], bfr[4];
    #pragma unroll
    for (int m = 0; m < 4; ++m) af[m] = *reinterpret_cast<const bf16x8*>(&As[wr + m * 16 + fr][fk]);
    #pragma unroll
    for (int n = 0; n < 4; ++n) bfr[n] = *reinterpret_cast<const bf16x8*>(&Bs[wc + n * 16 + fr][fk]);
    #pragma unroll
    for (int m = 0; m < 4; ++m)
      #pragma unroll
      for (int n = 0; n < 4; ++n)
        acc[m][n] = __builtin_amdgcn_mfma_f32_16x16x32_bf16(af[m], bfr[n], acc[m][n], 0, 0, 0);
    __syncthreads();
  }

  // epilogue: C/D layout (verified m89): col = lane&15, row = (lane>>4)*4 + i
  #pragma unroll
  for (int n = 0; n < 4; ++n) {
    const int col = bcol + wc + n * 16 + fr;
    const float bv = bias[col];
    #pragma unroll
    for (int m = 0; m < 4; ++m) {
      const long row0 = brow + wr + m * 16 + (lane >> 4) * 4;
      #pragma unroll
      for (int i = 0; i < 4; ++i) {
        float v = acc[m][n][i] + bv;
        if (RELU) v = fmaxf(v, 0.0f);
        if (BF16OUT) outb[(row0 + i) * DFEAT + col] = f2bf(v);
        else         outf[(row0 + i) * DFEAT + col] = v;
      }
    }
  }
}

extern "C" void kernel_launch(void* const* d_in, const int* in_sizes, int n_in,
                              void* d_out, int out_size, void* d_ws, size_t ws_size,
                              hipStream_t stream) {
  const float* fw_in   = (const float*)d_in[0];
  const float* bw_in   = (const float*)d_in[1];
  const float* edge_in = (const float*)d_in[2];
  const int* fw_adj    = (const int*)d_in[3];
  const int* bw_adj    = (const int*)d_in[4];
  const int* fw_eid    = (const int*)d_in[5];
  const int* bw_eid    = (const int*)d_in[6];
  const int* fw_dep    = (const int*)d_in[7];
  const int* bw_dep    = (const int*)d_in[8];
  const float* Wfc     = (const float*)d_in[9];
  const float* bfc     = (const float*)d_in[10];
  const float* Wbc     = (const float*)d_in[11];
  const float* bbc     = (const float*)d_in[12];
  const float* Wedge   = (const float*)d_in[13];
  const float* bedge   = (const float*)d_in[14];
  float* out_f = (float*)d_out;

  char* w = (char*)d_ws;
  auto alloc = [&](size_t b) { char* p = w; w += (b + 255) & ~(size_t)255; return p; };
  const size_t nodeB = (size_t)N_NODES * DFEAT * 2;
  const size_t edgeB = (size_t)N_EDGES * DFEAT * 2;
  unsigned short* Ff0 = (unsigned short*)alloc(nodeB);
  unsigned short* Ff1 = (unsigned short*)alloc(nodeB);
  unsigned short* Fb0 = (unsigned short*)alloc(nodeB);
  unsigned short* Fb1 = (unsigned short*)alloc(nodeB);
  unsigned short* Mf  = (unsigned short*)alloc(nodeB);
  unsigned short* Mb  = (unsigned short*)alloc(nodeB);
  unsigned short* Ee0 = (unsigned short*)alloc(edgeB);
  unsigned short* Ee1 = (unsigned short*)alloc(edgeB);
  unsigned short* Df  = (unsigned short*)alloc(edgeB);
  unsigned short* Db  = (unsigned short*)alloc(edgeB);
  unsigned short* WfT = (unsigned short*)alloc((size_t)1024 * 512 * 2);
  unsigned short* WbT = (unsigned short*)alloc((size_t)1024 * 512 * 2);
  unsigned short* WeT = (unsigned short*)alloc((size_t)1536 * 512 * 2);
  if ((size_t)(w - (char*)d_ws) > ws_size) return;  // insufficient workspace: bail cleanly

  // one-time per launch: weight transposes + feature converts
  transpose_w<<<dim3(1024 / 32, 512 / 32), dim3(32, 8), 0, stream>>>(Wfc, WfT, 1024);
  transpose_w<<<dim3(1024 / 32, 512 / 32), dim3(32, 8), 0, stream>>>(Wbc, WbT, 1024);
  transpose_w<<<dim3(1536 / 32, 512 / 32), dim3(32, 8), 0, stream>>>(Wedge, WeT, 1536);
  {
    const long nn = (long)N_NODES * DFEAT, ne = (long)N_EDGES * DFEAT;
    cvt_f32_bf16<<<(int)(nn / 4 / 256), 256, 0, stream>>>(fw_in, Ff0, nn);
    cvt_f32_bf16<<<(int)(nn / 4 / 256), 256, 0, stream>>>(bw_in, Fb0, nn);
    cvt_f32_bf16<<<(int)(ne / 4 / 256), 256, 0, stream>>>(edge_in, Ee0, ne);
  }

  unsigned short *Ffc = Ff0, *Ffn = Ff1, *Fbc = Fb0, *Fbn = Fb1, *Eec = Ee0, *Een = Ee1;
  const dim3 gn(N_NODES / 128, 4), ge(N_EDGES / 128, 4);

  for (int k = 0; k < 3; ++k) {
    nbr_mean_kernel<<<N_NODES / 4, 256, 0, stream>>>(Ffc, Eec, fw_adj, fw_eid, Mf, N_NODES);
    nbr_mean_kernel<<<N_NODES / 4, 256, 0, stream>>>(Fbc, Eec, bw_adj, bw_eid, Mb, N_NODES);
    if (k < 2) {
      gemm_seg<2, true, true><<<gn, 256, 0, stream>>>(Ffc, Mf, nullptr, WfT, bfc, Ffn, nullptr);
      gemm_seg<2, true, true><<<gn, 256, 0, stream>>>(Fbc, Mb, nullptr, WbT, bbc, Fbn, nullptr);
      edge_dep_kernel<<<N_EDGES / 4, 256, 0, stream>>>(Ffn, Fbn, fw_dep, bw_dep, Df, Db, N_EDGES);
      gemm_seg<3, true, true><<<ge, 256, 0, stream>>>(Eec, Df, Db, WeT, bedge, Een, nullptr);
      unsigned short* t;
      t = Ffc; Ffc = Ffn; Ffn = t;
      t = Fbc; Fbc = Fbn; Fbn = t;
      t = Eec; Eec = Een; Een = t;
    } else {
      gemm_seg<2, false, false><<<gn, 256, 0, stream>>>(Ffc, Mf, nullptr, WfT, bfc, nullptr, out_f);
      gemm_seg<2, false, false><<<gn, 256, 0, stream>>>(Fbc, Mb, nullptr, WbT, bbc, nullptr,
                                                        out_f + (long)N_NODES * DFEAT);
    }
  }
}

// Round 2
// 539.591 us; speedup vs baseline: 1.2110x; 1.2110x over previous
//
#include <hip/hip_runtime.h>
#include <hip/hip_bf16.h>

#define N_NODES 8192
#define N_EDGES 32768
#define DFEAT   512

typedef __attribute__((ext_vector_type(8))) short          bf16x8;
typedef __attribute__((ext_vector_type(4))) float          f32x4;
typedef __attribute__((ext_vector_type(8))) unsigned short u16x8;

__device__ __forceinline__ float bf2f(unsigned short u) {
  union { unsigned int i; float f; } x; x.i = ((unsigned int)u) << 16; return x.f;
}
__device__ __forceinline__ unsigned short f2bf(float f) {
  __hip_bfloat16 h = __float2bfloat16(f);
  return *reinterpret_cast<unsigned short*>(&h);
}

#define GLDS16(gp, lp) __builtin_amdgcn_global_load_lds( \
    (const __attribute__((address_space(1))) void*)(gp),  \
    (__attribute__((address_space(3))) void*)(lp), 16, 0, 0)

// ---------------- weight transpose fp32[K][512] -> bf16[512][K] ----------------
__global__ void transpose_w(const float* __restrict__ W, unsigned short* __restrict__ WT, int K) {
  __shared__ float tile[32][33];
  const int k0 = blockIdx.x * 32, n0 = blockIdx.y * 32;
  const int tx = threadIdx.x, ty = threadIdx.y;
  #pragma unroll
  for (int i = ty; i < 32; i += 8)
    tile[i][tx] = W[(long)(k0 + i) * DFEAT + n0 + tx];
  __syncthreads();
  #pragma unroll
  for (int i = ty; i < 32; i += 8)
    WT[(long)(n0 + i) * K + k0 + tx] = f2bf(tile[tx][i]);
}

// ---------------- merged fp32 -> bf16 convert for fw/bw/edge ----------------
__global__ void cvt3(const float* __restrict__ a, const float* __restrict__ b,
                     const float* __restrict__ c,
                     unsigned short* __restrict__ da, unsigned short* __restrict__ db,
                     unsigned short* __restrict__ dc, long na, long nc) {
  long i = ((long)blockIdx.x * blockDim.x + threadIdx.x) * 4;
  const float* s; unsigned short* d; long off;
  if (i < na)           { s = a; d = da; off = i; }
  else if (i < 2 * na)  { s = b; d = db; off = i - na; }
  else if (i < 2 * na + nc) { s = c; d = dc; off = i - 2 * na; }
  else return;
  float4 v = *reinterpret_cast<const float4*>(&s[off]);
  ushort4 o = { f2bf(v.x), f2bf(v.y), f2bf(v.z), f2bf(v.w) };
  *reinterpret_cast<ushort4*>(&d[off]) = o;
}

// ---------------- gather helper: accumulate rows (batched loads for MLP) ----------------
template<int W>
__device__ __forceinline__ void gather_acc(const unsigned short* __restrict__ base,
                                           const int* __restrict__ idxp, int c0,
                                           float* s, int& cnt) {
  int idx[W];
  u16x8 v[W];
  #pragma unroll
  for (int j = 0; j < W; ++j) idx[j] = idxp[j];
  #pragma unroll
  for (int j = 0; j < W; ++j) {
    int a = idx[j] >= 0 ? idx[j] : 0;
    v[j] = *reinterpret_cast<const u16x8*>(&base[(long)a * DFEAT + c0]);
  }
  #pragma unroll
  for (int j = 0; j < W; ++j) {
    if (idx[j] >= 0) {
      ++cnt;
      #pragma unroll
      for (int i = 0; i < 8; ++i) s[i] += bf2f(v[j][i]);
    }
  }
}

// ---------------- neighbor mean, fw+bw merged (blockIdx.y selects side) ----------------
__global__ __launch_bounds__(256) void nbr_mean2(
    const unsigned short* __restrict__ nodesF, const unsigned short* __restrict__ nodesB,
    const unsigned short* __restrict__ edges,
    const int* __restrict__ adjF, const int* __restrict__ adjB,
    const int* __restrict__ eidF, const int* __restrict__ eidB,
    unsigned short* __restrict__ dstF, unsigned short* __restrict__ dstB) {
  const int wave = threadIdx.x >> 6, lane = threadIdx.x & 63;
  const int n = blockIdx.x * 4 + wave;
  const unsigned short* nodes; const int* adj; const int* eid; unsigned short* dst;
  if (blockIdx.y == 0) { nodes = nodesF; adj = adjF; eid = eidF; dst = dstF; }
  else                 { nodes = nodesB; adj = adjB; eid = eidB; dst = dstB; }
  const int c0 = lane * 8;
  float s[8] = {0, 0, 0, 0, 0, 0, 0, 0};
  int cnt = 0;
  gather_acc<8>(nodes, adj + (long)n * 16, c0, s, cnt);
  gather_acc<8>(nodes, adj + (long)n * 16 + 8, c0, s, cnt);
  gather_acc<8>(edges, eid + (long)n * 16, c0, s, cnt);
  gather_acc<8>(edges, eid + (long)n * 16 + 8, c0, s, cnt);
  const float inv = 1.0f / (float)cnt;
  u16x8 o;
  #pragma unroll
  for (int i = 0; i < 8; ++i) o[i] = f2bf(s[i] * inv);
  *reinterpret_cast<u16x8*>(&dst[(long)n * DFEAT + c0]) = o;
}

// ---------------- fused edge update: Een = relu(Ge + mean(Pf[fdep]) + mean(Pb[bdep])) ----------------
__global__ __launch_bounds__(256) void edge_fuse(
    const unsigned short* __restrict__ Pf, const unsigned short* __restrict__ Pb,
    const unsigned short* __restrict__ Ge,
    const int* __restrict__ fdep, const int* __restrict__ bdep,
    unsigned short* __restrict__ Een) {
  const int wave = threadIdx.x >> 6, lane = threadIdx.x & 63;
  const int e = blockIdx.x * 4 + wave;
  const int c0 = lane * 8;
  float sf[8] = {0, 0, 0, 0, 0, 0, 0, 0};
  float sb[8] = {0, 0, 0, 0, 0, 0, 0, 0};
  int fc = 0, bc = 0;
  gather_acc<8>(Pf, fdep + (long)e * 8, c0, sf, fc);
  gather_acc<8>(Pb, bdep + (long)e * 8, c0, sb, bc);
  const u16x8 gv = *reinterpret_cast<const u16x8*>(&Ge[(long)e * DFEAT + c0]);
  const float invf = 1.0f / (float)fc, invb = 1.0f / (float)bc;
  u16x8 o;
  #pragma unroll
  for (int i = 0; i < 8; ++i) {
    float v = bf2f(gv[i]) + sf[i] * invf + sb[i] * invb;
    o[i] = f2bf(fmaxf(v, 0.0f));
  }
  *reinterpret_cast<u16x8*>(&Een[(long)e * DFEAT + c0]) = o;
}

// ---------------- GEMM: C[·,512] = concat(A0[,A1]) @ Bt^T (+ bias) ----------------
// A segments: bf16 [M][512] row-major. Bt: bf16 [512][LDB] (pre-transposed weights,
// possibly offset into a wider matrix). m97 structure: 128x128 tile, BK=32,
// 4 waves of 64x64, global_load_lds staging. blockIdx.z selects arg set.
struct GArg {
  const unsigned short* A0;
  const unsigned short* A1;
  const unsigned short* Bt;
  const float* bias;
  unsigned short* outb;
  float* outf;
};

template<int K, int LDB, int NSEG, int SWZQ, bool RELU, bool BIAS, bool BF16OUT>
__global__ __launch_bounds__(256, 2) void gemm2(GArg ga, GArg gb) {
  const GArg g = blockIdx.z ? gb : ga;
  __shared__ unsigned short As[128][32];
  __shared__ unsigned short Bs[128][32];
  const int tid = threadIdx.x;
  const int wave = tid >> 6, lane = tid & 63;
  // m204 bijective XCD swizzle (nwg = 8*SWZQ), then col-fastest decode (NCOL=4)
  const int bid = blockIdx.x;
  const int swz = (bid & 7) * SWZQ + (bid >> 3);
  const long brow = (long)(swz >> 2) * 128;
  const int bcol = (swz & 3) * 128;
  const int wr = (wave >> 1) * 64, wc = (wave & 1) * 64;

  f32x4 acc[4][4] = {};

  const int srow = lane >> 2;         // 0..15
  const int scol = (lane & 3) * 8;    // 0,8,16,24
  const int rb = wave * 32;           // rows this wave stages
  unsigned short* As0 = &As[rb][0];
  unsigned short* As1 = &As[rb + 16][0];
  unsigned short* Bs0 = &Bs[rb][0];
  unsigned short* Bs1 = &Bs[rb + 16][0];

  const int fr = lane & 15;
  const int fk = (lane >> 4) * 8;

  for (int kt = 0; kt < K / 32; ++kt) {
    const unsigned short* Aseg;
    int kcol;
    if (NSEG == 1) { Aseg = g.A0; kcol = kt * 32; }
    else           { Aseg = (kt < 16) ? g.A0 : g.A1; kcol = (kt & 15) * 32; }
    GLDS16(Aseg + (brow + rb + srow) * DFEAT + kcol + scol, As0);
    GLDS16(Aseg + (brow + rb + 16 + srow) * DFEAT + kcol + scol, As1);
    const long bk = (long)kt * 32;
    GLDS16(g.Bt + (long)(bcol + rb + srow) * LDB + bk + scol, Bs0);
    GLDS16(g.Bt + (long)(bcol + rb + 16 + srow) * LDB + bk + scol, Bs1);
    __syncthreads();
    bf16x8 af[4], bfr[4];
    #pragma unroll
    for (int m = 0; m < 4; ++m) af[m] = *reinterpret_cast<const bf16x8*>(&As[wr + m * 16 + fr][fk]);
    #pragma unroll
    for (int n = 0; n < 4; ++n) bfr[n] = *reinterpret_cast<const bf16x8*>(&Bs[wc + n * 16 + fr][fk]);
    #pragma unroll
    for (int m = 0; m < 4; ++m)
      #pragma unroll
      for (int n = 0; n < 4; ++n)
        acc[m][n] = __builtin_amdgcn_mfma_f32_16x16x32_bf16(af[m], bfr[n], acc[m][n], 0, 0, 0);
    __syncthreads();
  }

  // epilogue: C/D layout (verified m89): col = lane&15, row = (lane>>4)*4 + i
  #pragma unroll
  for (int n = 0; n < 4; ++n) {
    const int col = bcol + wc + n * 16 + fr;
    float bv = 0.0f;
    if (BIAS) bv = g.bias[col];
    #pragma unroll
    for (int m = 0; m < 4; ++m) {
      const long row0 = brow + wr + m * 16 + (lane >> 4) * 4;
      #pragma unroll
      for (int i = 0; i < 4; ++i) {
        float v = acc[m][n][i] + bv;
        if (RELU) v = fmaxf(v, 0.0f);
        if (BF16OUT) g.outb[(row0 + i) * DFEAT + col] = f2bf(v);
        else         g.outf[(row0 + i) * DFEAT + col] = v;
      }
    }
  }
}

extern "C" void kernel_launch(void* const* d_in, const int* in_sizes, int n_in,
                              void* d_out, int out_size, void* d_ws, size_t ws_size,
                              hipStream_t stream) {
  const float* fw_in   = (const float*)d_in[0];
  const float* bw_in   = (const float*)d_in[1];
  const float* edge_in = (const float*)d_in[2];
  const int* fw_adj    = (const int*)d_in[3];
  const int* bw_adj    = (const int*)d_in[4];
  const int* fw_eid    = (const int*)d_in[5];
  const int* bw_eid    = (const int*)d_in[6];
  const int* fw_dep    = (const int*)d_in[7];
  const int* bw_dep    = (const int*)d_in[8];
  const float* Wfc     = (const float*)d_in[9];
  const float* bfc     = (const float*)d_in[10];
  const float* Wbc     = (const float*)d_in[11];
  const float* bbc     = (const float*)d_in[12];
  const float* Wedge   = (const float*)d_in[13];
  const float* bedge   = (const float*)d_in[14];
  float* out_f = (float*)d_out;

  char* w = (char*)d_ws;
  auto alloc = [&](size_t b) { char* p = w; w += (b + 255) & ~(size_t)255; return p; };
  const size_t nodeB = (size_t)N_NODES * DFEAT * 2;
  const size_t edgeB = (size_t)N_EDGES * DFEAT * 2;
  unsigned short* Ff0 = (unsigned short*)alloc(nodeB);
  unsigned short* Ff1 = (unsigned short*)alloc(nodeB);
  unsigned short* Fb0 = (unsigned short*)alloc(nodeB);
  unsigned short* Fb1 = (unsigned short*)alloc(nodeB);
  unsigned short* Mf  = (unsigned short*)alloc(nodeB);
  unsigned short* Mb  = (unsigned short*)alloc(nodeB);
  unsigned short* Pf  = (unsigned short*)alloc(nodeB);
  unsigned short* Pb  = (unsigned short*)alloc(nodeB);
  unsigned short* Ee0 = (unsigned short*)alloc(edgeB);
  unsigned short* Ee1 = (unsigned short*)alloc(edgeB);
  unsigned short* Ge  = (unsigned short*)alloc(edgeB);
  unsigned short* WfT = (unsigned short*)alloc((size_t)1024 * 512 * 2);
  unsigned short* WbT = (unsigned short*)alloc((size_t)1024 * 512 * 2);
  unsigned short* WeT = (unsigned short*)alloc((size_t)1536 * 512 * 2);
  if ((size_t)(w - (char*)d_ws) > ws_size) return;  // insufficient workspace: bail cleanly

  // one-time per launch: weight transposes + feature converts
  transpose_w<<<dim3(1024 / 32, 512 / 32), dim3(32, 8), 0, stream>>>(Wfc, WfT, 1024);
  transpose_w<<<dim3(1024 / 32, 512 / 32), dim3(32, 8), 0, stream>>>(Wbc, WbT, 1024);
  transpose_w<<<dim3(1536 / 32, 512 / 32), dim3(32, 8), 0, stream>>>(Wedge, WeT, 1536);
  {
    const long nn = (long)N_NODES * DFEAT, ne = (long)N_EDGES * DFEAT;
    const long tot = 2 * nn + ne;
    cvt3<<<(int)(tot / 4 / 256), 256, 0, stream>>>(fw_in, bw_in, edge_in, Ff0, Fb0, Ee0, nn, ne);
  }

  unsigned short *Ffc = Ff0, *Ffn = Ff1, *Fbc = Fb0, *Fbn = Fb1, *Eec = Ee0, *Een = Ee1;

  for (int k = 0; k < 3; ++k) {
    nbr_mean2<<<dim3(N_NODES / 4, 2), 256, 0, stream>>>(
        Ffc, Fbc, Eec, fw_adj, bw_adj, fw_eid, bw_eid, Mf, Mb);
    if (k < 2) {
      // node update (fw+bw in one dispatch): Ffn = relu([Ffc|Mf]@Wfc + bfc)
      gemm2<1024, 1024, 2, 32, true, true, true><<<dim3(256, 1, 2), 256, 0, stream>>>(
          GArg{Ffc, Mf, WfT, bfc, Ffn, nullptr}, GArg{Fbc, Mb, WbT, bbc, Fbn, nullptr});
      // projections: Pf = Ffn @ We2, Pb = Fbn @ We3 (no bias/relu)
      gemm2<512, 1536, 1, 32, false, false, true><<<dim3(256, 1, 2), 256, 0, stream>>>(
          GArg{Ffn, nullptr, WeT + 512, nullptr, Pf, nullptr},
          GArg{Fbn, nullptr, WeT + 1024, nullptr, Pb, nullptr});
      // edge partial: Ge = Eec @ We1 + bedge (relu deferred to fuse)
      gemm2<512, 1536, 1, 128, false, true, true><<<dim3(1024, 1, 1), 256, 0, stream>>>(
          GArg{Eec, nullptr, WeT, bedge, Ge, nullptr},
          GArg{Eec, nullptr, WeT, bedge, Ge, nullptr});
      // Een = relu(Ge + mean(Pf[fdep]) + mean(Pb[bdep]))
      edge_fuse<<<N_EDGES / 4, 256, 0, stream>>>(Pf, Pb, Ge, fw_dep, bw_dep, Een);
      unsigned short* t;
      t = Ffc; Ffc = Ffn; Ffn = t;
      t = Fbc; Fbc = Fbn; Fbn = t;
      t = Eec; Eec = Een; Een = t;
    } else {
      gemm2<1024, 1024, 2, 32, false, true, false><<<dim3(256, 1, 2), 256, 0, stream>>>(
          GArg{Ffc, Mf, WfT, bfc, nullptr, out_f},
          GArg{Fbc, Mb, WbT, bbc, nullptr, out_f + (long)N_NODES * DFEAT});
    }
  }
}

// Round 4
// 533.052 us; speedup vs baseline: 1.2259x; 1.0123x over previous
//
#include <hip/hip_runtime.h>
#include <hip/hip_bf16.h>

#define N_NODES 8192
#define N_EDGES 32768
#define DFEAT   512

typedef __attribute__((ext_vector_type(8))) short          bf16x8;
typedef __attribute__((ext_vector_type(4))) float          f32x4;
typedef __attribute__((ext_vector_type(8))) unsigned short u16x8;

__device__ __forceinline__ float bf2f(unsigned short u) {
  union { unsigned int i; float f; } x; x.i = ((unsigned int)u) << 16; return x.f;
}
__device__ __forceinline__ unsigned short f2bf(float f) {
  __hip_bfloat16 h = __float2bfloat16(f);
  return *reinterpret_cast<unsigned short*>(&h);
}

#define GLDS16(gp, lp) __builtin_amdgcn_global_load_lds( \
    (const __attribute__((address_space(1))) void*)(gp),  \
    (__attribute__((address_space(3))) void*)(lp), 16, 0, 0)

// keep 16 in-flight gather vectors live simultaneously (prevents load sinking)
#define KEEP16(a) asm volatile("" :: \
  "v"(a[0]), "v"(a[1]), "v"(a[2]),  "v"(a[3]),  "v"(a[4]),  "v"(a[5]),  "v"(a[6]),  "v"(a[7]), \
  "v"(a[8]), "v"(a[9]), "v"(a[10]), "v"(a[11]), "v"(a[12]), "v"(a[13]), "v"(a[14]), "v"(a[15]))

// ---------------- merged weight transposes fp32[K][512] -> bf16[512][K] ----------------
__global__ void transpose_w3(const float* __restrict__ W0, const float* __restrict__ W1,
                             const float* __restrict__ W2,
                             unsigned short* __restrict__ T0, unsigned short* __restrict__ T1,
                             unsigned short* __restrict__ T2) {
  __shared__ float tile[32][33];
  const float* W; unsigned short* WT; int K;
  if (blockIdx.z == 0)      { W = W0; WT = T0; K = 1024; }
  else if (blockIdx.z == 1) { W = W1; WT = T1; K = 1024; }
  else                      { W = W2; WT = T2; K = 1536; }
  const int k0 = blockIdx.x * 32, n0 = blockIdx.y * 32;
  if (k0 >= K) return;
  const int tx = threadIdx.x, ty = threadIdx.y;
  #pragma unroll
  for (int i = ty; i < 32; i += 8)
    tile[i][tx] = W[(long)(k0 + i) * DFEAT + n0 + tx];
  __syncthreads();
  #pragma unroll
  for (int i = ty; i < 32; i += 8)
    WT[(long)(n0 + i) * K + k0 + tx] = f2bf(tile[tx][i]);
}

// ---------------- merged fp32 -> bf16 convert for fw/bw/edge ----------------
__global__ void cvt3(const float* __restrict__ a, const float* __restrict__ b,
                     const float* __restrict__ c,
                     unsigned short* __restrict__ da, unsigned short* __restrict__ db,
                     unsigned short* __restrict__ dc, long na, long nc) {
  long i = ((long)blockIdx.x * blockDim.x + threadIdx.x) * 4;
  const float* s; unsigned short* d; long off;
  if (i < na)           { s = a; d = da; off = i; }
  else if (i < 2 * na)  { s = b; d = db; off = i - na; }
  else if (i < 2 * na + nc) { s = c; d = dc; off = i - 2 * na; }
  else return;
  float4 v = *reinterpret_cast<const float4*>(&s[off]);
  ushort4 o = { f2bf(v.x), f2bf(v.y), f2bf(v.z), f2bf(v.w) };
  *reinterpret_cast<ushort4*>(&d[off]) = o;
}

// ---------------- neighbor mean, fw+bw merged; deep-MLP gather ----------------
__global__ __launch_bounds__(256, 2) void nbr_mean2(
    const unsigned short* __restrict__ nodesF, const unsigned short* __restrict__ nodesB,
    const unsigned short* __restrict__ edges,
    const int* __restrict__ adjF, const int* __restrict__ adjB,
    const int* __restrict__ eidF, const int* __restrict__ eidB,
    unsigned short* __restrict__ dstF, unsigned short* __restrict__ dstB) {
  const int wave = threadIdx.x >> 6, lane = threadIdx.x & 63;
  const int n = blockIdx.x * 4 + wave;
  const unsigned short* nodes; const int* adj; const int* eid; unsigned short* dst;
  if (blockIdx.y == 0) { nodes = nodesF; adj = adjF; eid = eidF; dst = dstF; }
  else                 { nodes = nodesB; adj = adjB; eid = eidB; dst = dstB; }
  const int c0 = lane * 8;

  int ia[16], ie[16];
  {
    const int4* pa = reinterpret_cast<const int4*>(adj + (long)n * 16);
    const int4* pe = reinterpret_cast<const int4*>(eid + (long)n * 16);
    #pragma unroll
    for (int q = 0; q < 4; ++q) {
      int4 t = pa[q];
      ia[q * 4] = t.x; ia[q * 4 + 1] = t.y; ia[q * 4 + 2] = t.z; ia[q * 4 + 3] = t.w;
      int4 u = pe[q];
      ie[q * 4] = u.x; ie[q * 4 + 1] = u.y; ie[q * 4 + 2] = u.z; ie[q * 4 + 3] = u.w;
    }
  }

  // issue all 32 row loads before any accumulation
  u16x8 va[16], ve[16];
  #pragma unroll
  for (int j = 0; j < 16; ++j) {
    const int a = ia[j] >= 0 ? ia[j] : 0;
    va[j] = *reinterpret_cast<const u16x8*>(&nodes[(long)a * DFEAT + c0]);
  }
  #pragma unroll
  for (int j = 0; j < 16; ++j) {
    const int a = ie[j] >= 0 ? ie[j] : 0;
    ve[j] = *reinterpret_cast<const u16x8*>(&edges[(long)a * DFEAT + c0]);
  }
  KEEP16(va);
  KEEP16(ve);

  float s[8] = {0, 0, 0, 0, 0, 0, 0, 0};
  int cnt = 0;
  #pragma unroll
  for (int j = 0; j < 16; ++j) {
    if (ia[j] >= 0) {
      ++cnt;
      #pragma unroll
      for (int i = 0; i < 8; ++i) s[i] += bf2f(va[j][i]);
    }
  }
  #pragma unroll
  for (int j = 0; j < 16; ++j) {
    if (ie[j] >= 0) {
      ++cnt;
      #pragma unroll
      for (int i = 0; i < 8; ++i) s[i] += bf2f(ve[j][i]);
    }
  }
  const float inv = 1.0f / (float)cnt;
  u16x8 o;
  #pragma unroll
  for (int i = 0; i < 8; ++i) o[i] = f2bf(s[i] * inv);
  *reinterpret_cast<u16x8*>(&dst[(long)n * DFEAT + c0]) = o;
}

// ---------------- fused edge update: Een = relu(Ge + mean(Pf[fdep]) + mean(Pb[bdep])) ----------------
__global__ __launch_bounds__(256, 2) void edge_fuse(
    const unsigned short* __restrict__ Pf, const unsigned short* __restrict__ Pb,
    const unsigned short* __restrict__ Ge,
    const int* __restrict__ fdep, const int* __restrict__ bdep,
    unsigned short* __restrict__ Een) {
  const int wave = threadIdx.x >> 6, lane = threadIdx.x & 63;
  const int e = blockIdx.x * 4 + wave;
  const int c0 = lane * 8;

  int idx[16];
  {
    const int4* pf = reinterpret_cast<const int4*>(fdep + (long)e * 8);
    const int4* pb = reinterpret_cast<const int4*>(bdep + (long)e * 8);
    #pragma unroll
    for (int q = 0; q < 2; ++q) {
      int4 t = pf[q];
      idx[q * 4] = t.x; idx[q * 4 + 1] = t.y; idx[q * 4 + 2] = t.z; idx[q * 4 + 3] = t.w;
      int4 u = pb[q];
      idx[8 + q * 4] = u.x; idx[8 + q * 4 + 1] = u.y; idx[8 + q * 4 + 2] = u.z; idx[8 + q * 4 + 3] = u.w;
    }
  }

  const u16x8 gv = *reinterpret_cast<const u16x8*>(&Ge[(long)e * DFEAT + c0]);

  u16x8 v[16];
  #pragma unroll
  for (int j = 0; j < 8; ++j) {
    const int a = idx[j] >= 0 ? idx[j] : 0;
    v[j] = *reinterpret_cast<const u16x8*>(&Pf[(long)a * DFEAT + c0]);
  }
  #pragma unroll
  for (int j = 0; j < 8; ++j) {
    const int a = idx[8 + j] >= 0 ? idx[8 + j] : 0;
    v[8 + j] = *reinterpret_cast<const u16x8*>(&Pb[(long)a * DFEAT + c0]);
  }
  KEEP16(v);

  float sf[8] = {0, 0, 0, 0, 0, 0, 0, 0};
  float sb[8] = {0, 0, 0, 0, 0, 0, 0, 0};
  int fc = 0, bc = 0;
  #pragma unroll
  for (int j = 0; j < 8; ++j) {
    if (idx[j] >= 0) {
      ++fc;
      #pragma unroll
      for (int i = 0; i < 8; ++i) sf[i] += bf2f(v[j][i]);
    }
  }
  #pragma unroll
  for (int j = 0; j < 8; ++j) {
    if (idx[8 + j] >= 0) {
      ++bc;
      #pragma unroll
      for (int i = 0; i < 8; ++i) sb[i] += bf2f(v[8 + j][i]);
    }
  }
  const float invf = 1.0f / (float)fc, invb = 1.0f / (float)bc;
  u16x8 o;
  #pragma unroll
  for (int i = 0; i < 8; ++i) {
    float x = bf2f(gv[i]) + sf[i] * invf + sb[i] * invb;
    o[i] = f2bf(fmaxf(x, 0.0f));
  }
  *reinterpret_cast<u16x8*>(&Een[(long)e * DFEAT + c0]) = o;
}

// ---------------- GEMM: C[·,512] = concat(A0[,A1]) @ Bt^T (+ bias) ----------------
// A segments: bf16 [M][512] row-major. Bt: bf16 [512][LDB] (pre-transposed weights,
// possibly offset into a wider matrix). m97 structure: 128x128 tile, BK=32,
// 4 waves of 64x64, global_load_lds staging. blockIdx.z selects arg set.
struct GArg {
  const unsigned short* A0;
  const unsigned short* A1;
  const unsigned short* Bt;
  const float* bias;
  unsigned short* outb;
  float* outf;
};

template<int K, int LDB, int NSEG, int SWZQ, bool RELU, bool BIAS, bool BF16OUT>
__global__ __launch_bounds__(256, 2) void gemm2(GArg ga, GArg gb) {
  const GArg g = blockIdx.z ? gb : ga;
  __shared__ unsigned short As[128][32];
  __shared__ unsigned short Bs[128][32];
  const int tid = threadIdx.x;
  const int wave = tid >> 6, lane = tid & 63;
  // m204 bijective XCD swizzle (nwg = 8*SWZQ), then col-fastest decode (NCOL=4)
  const int bid = blockIdx.x;
  const int swz = (bid & 7) * SWZQ + (bid >> 3);
  const long brow = (long)(swz >> 2) * 128;
  const int bcol = (swz & 3) * 128;
  const int wr = (wave >> 1) * 64, wc = (wave & 1) * 64;

  f32x4 acc[4][4] = {};

  const int srow = lane >> 2;         // 0..15
  const int scol = (lane & 3) * 8;    // 0,8,16,24
  const int rb = wave * 32;           // rows this wave stages
  unsigned short* As0 = &As[rb][0];
  unsigned short* As1 = &As[rb + 16][0];
  unsigned short* Bs0 = &Bs[rb][0];
  unsigned short* Bs1 = &Bs[rb + 16][0];

  const int fr = lane & 15;
  const int fk = (lane >> 4) * 8;

  for (int kt = 0; kt < K / 32; ++kt) {
    const unsigned short* Aseg;
    int kcol;
    if (NSEG == 1) { Aseg = g.A0; kcol = kt * 32; }
    else           { Aseg = (kt < 16) ? g.A0 : g.A1; kcol = (kt & 15) * 32; }
    GLDS16(Aseg + (brow + rb + srow) * DFEAT + kcol + scol, As0);
    GLDS16(Aseg + (brow + rb + 16 + srow) * DFEAT + kcol + scol, As1);
    const long bk = (long)kt * 32;
    GLDS16(g.Bt + (long)(bcol + rb + srow) * LDB + bk + scol, Bs0);
    GLDS16(g.Bt + (long)(bcol + rb + 16 + srow) * LDB + bk + scol, Bs1);
    __syncthreads();
    bf16x8 af[4], bfr[4];
    #pragma unroll
    for (int m = 0; m < 4; ++m) af[m] = *reinterpret_cast<const bf16x8*>(&As[wr + m * 16 + fr][fk]);
    #pragma unroll
    for (int n = 0; n < 4; ++n) bfr[n] = *reinterpret_cast<const bf16x8*>(&Bs[wc + n * 16 + fr][fk]);
    #pragma unroll
    for (int m = 0; m < 4; ++m)
      #pragma unroll
      for (int n = 0; n < 4; ++n)
        acc[m][n] = __builtin_amdgcn_mfma_f32_16x16x32_bf16(af[m], bfr[n], acc[m][n], 0, 0, 0);
    __syncthreads();
  }

  // epilogue: C/D layout (verified m89): col = lane&15, row = (lane>>4)*4 + i
  #pragma unroll
  for (int n = 0; n < 4; ++n) {
    const int col = bcol + wc + n * 16 + fr;
    float bv = 0.0f;
    if (BIAS) bv = g.bias[col];
    #pragma unroll
    for (int m = 0; m < 4; ++m) {
      const long row0 = brow + wr + m * 16 + (lane >> 4) * 4;
      #pragma unroll
      for (int i = 0; i < 4; ++i) {
        float v = acc[m][n][i] + bv;
        if (RELU) v = fmaxf(v, 0.0f);
        if (BF16OUT) g.outb[(row0 + i) * DFEAT + col] = f2bf(v);
        else         g.outf[(row0 + i) * DFEAT + col] = v;
      }
    }
  }
}

extern "C" void kernel_launch(void* const* d_in, const int* in_sizes, int n_in,
                              void* d_out, int out_size, void* d_ws, size_t ws_size,
                              hipStream_t stream) {
  const float* fw_in   = (const float*)d_in[0];
  const float* bw_in   = (const float*)d_in[1];
  const float* edge_in = (const float*)d_in[2];
  const int* fw_adj    = (const int*)d_in[3];
  const int* bw_adj    = (const int*)d_in[4];
  const int* fw_eid    = (const int*)d_in[5];
  const int* bw_eid    = (const int*)d_in[6];
  const int* fw_dep    = (const int*)d_in[7];
  const int* bw_dep    = (const int*)d_in[8];
  const float* Wfc     = (const float*)d_in[9];
  const float* bfc     = (const float*)d_in[10];
  const float* Wbc     = (const float*)d_in[11];
  const float* bbc     = (const float*)d_in[12];
  const float* Wedge   = (const float*)d_in[13];
  const float* bedge   = (const float*)d_in[14];
  float* out_f = (float*)d_out;

  char* w = (char*)d_ws;
  auto alloc = [&](size_t b) { char* p = w; w += (b + 255) & ~(size_t)255; return p; };
  const size_t nodeB = (size_t)N_NODES * DFEAT * 2;
  const size_t edgeB = (size_t)N_EDGES * DFEAT * 2;
  unsigned short* Ff0 = (unsigned short*)alloc(nodeB);
  unsigned short* Ff1 = (unsigned short*)alloc(nodeB);
  unsigned short* Fb0 = (unsigned short*)alloc(nodeB);
  unsigned short* Fb1 = (unsigned short*)alloc(nodeB);
  unsigned short* Mf  = (unsigned short*)alloc(nodeB);
  unsigned short* Mb  = (unsigned short*)alloc(nodeB);
  unsigned short* Pf  = (unsigned short*)alloc(nodeB);
  unsigned short* Pb  = (unsigned short*)alloc(nodeB);
  unsigned short* Ee0 = (unsigned short*)alloc(edgeB);
  unsigned short* Ee1 = (unsigned short*)alloc(edgeB);
  unsigned short* Ge  = (unsigned short*)alloc(edgeB);
  unsigned short* WfT = (unsigned short*)alloc((size_t)1024 * 512 * 2);
  unsigned short* WbT = (unsigned short*)alloc((size_t)1024 * 512 * 2);
  unsigned short* WeT = (unsigned short*)alloc((size_t)1536 * 512 * 2);
  if ((size_t)(w - (char*)d_ws) > ws_size) return;  // insufficient workspace: bail cleanly

  // one-time per launch: weight transposes + feature converts
  transpose_w3<<<dim3(48, 16, 3), dim3(32, 8), 0, stream>>>(Wfc, Wbc, Wedge, WfT, WbT, WeT);
  {
    const long nn = (long)N_NODES * DFEAT, ne = (long)N_EDGES * DFEAT;
    const long tot = 2 * nn + ne;
    cvt3<<<(int)(tot / 4 / 256), 256, 0, stream>>>(fw_in, bw_in, edge_in, Ff0, Fb0, Ee0, nn, ne);
  }

  unsigned short *Ffc = Ff0, *Ffn = Ff1, *Fbc = Fb0, *Fbn = Fb1, *Eec = Ee0, *Een = Ee1;

  for (int k = 0; k < 3; ++k) {
    nbr_mean2<<<dim3(N_NODES / 4, 2), 256, 0, stream>>>(
        Ffc, Fbc, Eec, fw_adj, bw_adj, fw_eid, bw_eid, Mf, Mb);
    if (k < 2) {
      // node update (fw+bw in one dispatch): Ffn = relu([Ffc|Mf]@Wfc + bfc)
      gemm2<1024, 1024, 2, 32, true, true, true><<<dim3(256, 1, 2), 256, 0, stream>>>(
          GArg{Ffc, Mf, WfT, bfc, Ffn, nullptr}, GArg{Fbc, Mb, WbT, bbc, Fbn, nullptr});
      // projections: Pf = Ffn @ We2, Pb = Fbn @ We3 (no bias/relu)
      gemm2<512, 1536, 1, 32, false, false, true><<<dim3(256, 1, 2), 256, 0, stream>>>(
          GArg{Ffn, nullptr, WeT + 512, nullptr, Pf, nullptr},
          GArg{Fbn, nullptr, WeT + 1024, nullptr, Pb, nullptr});
      // edge partial: Ge = Eec @ We1 + bedge (relu deferred to fuse)
      gemm2<512, 1536, 1, 128, false, true, true><<<dim3(1024, 1, 1), 256, 0, stream>>>(
          GArg{Eec, nullptr, WeT, bedge, Ge, nullptr},
          GArg{Eec, nullptr, WeT, bedge, Ge, nullptr});
      // Een = relu(Ge + mean(Pf[fdep]) + mean(Pb[bdep]))
      edge_fuse<<<N_EDGES / 4, 256, 0, stream>>>(Pf, Pb, Ge, fw_dep, bw_dep, Een);
      unsigned short* t;
      t = Ffc; Ffc = Ffn; Ffn = t;
      t = Fbc; Fbc = Fbn; Fbn = t;
      t = Eec; Eec = Een; Een = t;
    } else {
      gemm2<1024, 1024, 2, 32, false, true, false><<<dim3(256, 1, 2), 256, 0, stream>>>(
          GArg{Ffc, Mf, WfT, bfc, nullptr, out_f},
          GArg{Fbc, Mb, WbT, bbc, nullptr, out_f + (long)N_NODES * DFEAT});
    }
  }
}

// Round 5
// 526.383 us; speedup vs baseline: 1.2414x; 1.0127x over previous
//
#include <hip/hip_runtime.h>
#include <hip/hip_bf16.h>

#define N_NODES 8192
#define N_EDGES 32768
#define DFEAT   512

typedef __attribute__((ext_vector_type(8))) short          bf16x8;
typedef __attribute__((ext_vector_type(4))) float          f32x4;
typedef __attribute__((ext_vector_type(8))) unsigned short u16x8;

__device__ __forceinline__ float bf2f(unsigned short u) {
  union { unsigned int i; float f; } x; x.i = ((unsigned int)u) << 16; return x.f;
}
__device__ __forceinline__ unsigned short f2bf(float f) {
  __hip_bfloat16 h = __float2bfloat16(f);
  return *reinterpret_cast<unsigned short*>(&h);
}

#define GLDS16(gp, lp) __builtin_amdgcn_global_load_lds( \
    (const __attribute__((address_space(1))) void*)(gp),  \
    (__attribute__((address_space(3))) void*)(lp), 16, 0, 0)

// inline-asm 16B gather load: compiler cannot split/serialize these; the batch
// of asm defs stays resident until the explicit vmcnt wait.
__device__ __forceinline__ void gload16(u16x8& d, const unsigned short* p) {
  asm volatile("global_load_dwordx4 %0, %1, off" : "=v"(d) : "v"(p));
}
#define WAIT_VM(N) do { \
  asm volatile("s_waitcnt vmcnt(" #N ")" ::: "memory"); \
  __builtin_amdgcn_sched_barrier(0); \
} while (0)

// ---------------- merged weight transposes fp32[K][512] -> bf16[512][K] ----------------
__global__ void transpose_w3(const float* __restrict__ W0, const float* __restrict__ W1,
                             const float* __restrict__ W2,
                             unsigned short* __restrict__ T0, unsigned short* __restrict__ T1,
                             unsigned short* __restrict__ T2) {
  __shared__ float tile[32][33];
  const float* W; unsigned short* WT; int K;
  if (blockIdx.z == 0)      { W = W0; WT = T0; K = 1024; }
  else if (blockIdx.z == 1) { W = W1; WT = T1; K = 1024; }
  else                      { W = W2; WT = T2; K = 1536; }
  const int k0 = blockIdx.x * 32, n0 = blockIdx.y * 32;
  if (k0 >= K) return;
  const int tx = threadIdx.x, ty = threadIdx.y;
  #pragma unroll
  for (int i = ty; i < 32; i += 8)
    tile[i][tx] = W[(long)(k0 + i) * DFEAT + n0 + tx];
  __syncthreads();
  #pragma unroll
  for (int i = ty; i < 32; i += 8)
    WT[(long)(n0 + i) * K + k0 + tx] = f2bf(tile[tx][i]);
}

// ---------------- merged fp32 -> bf16 convert for fw/bw/edge ----------------
__global__ void cvt3(const float* __restrict__ a, const float* __restrict__ b,
                     const float* __restrict__ c,
                     unsigned short* __restrict__ da, unsigned short* __restrict__ db,
                     unsigned short* __restrict__ dc, long na, long nc) {
  long i = ((long)blockIdx.x * blockDim.x + threadIdx.x) * 4;
  const float* s; unsigned short* d; long off;
  if (i < na)           { s = a; d = da; off = i; }
  else if (i < 2 * na)  { s = b; d = db; off = i - na; }
  else if (i < 2 * na + nc) { s = c; d = dc; off = i - 2 * na; }
  else return;
  float4 v = *reinterpret_cast<const float4*>(&s[off]);
  ushort4 o = { f2bf(v.x), f2bf(v.y), f2bf(v.z), f2bf(v.w) };
  *reinterpret_cast<ushort4*>(&d[off]) = o;
}

// ---------------- neighbor mean, fw+bw merged; asm-batched gather ----------------
__global__ __launch_bounds__(256, 2) void nbr_mean2(
    const unsigned short* __restrict__ nodesF, const unsigned short* __restrict__ nodesB,
    const unsigned short* __restrict__ edges,
    const int* __restrict__ adjF, const int* __restrict__ adjB,
    const int* __restrict__ eidF, const int* __restrict__ eidB,
    unsigned short* __restrict__ dstF, unsigned short* __restrict__ dstB) {
  const int wave = threadIdx.x >> 6, lane = threadIdx.x & 63;
  const int n = blockIdx.x * 4 + wave;
  const unsigned short* nodes; const int* adj; const int* eid; unsigned short* dst;
  if (blockIdx.y == 0) { nodes = nodesF; adj = adjF; eid = eidF; dst = dstF; }
  else                 { nodes = nodesB; adj = adjB; eid = eidB; dst = dstB; }
  const int c0 = lane * 8;

  int ia[16], ie[16];
  {
    const int4* pa = reinterpret_cast<const int4*>(adj + (long)n * 16);
    const int4* pe = reinterpret_cast<const int4*>(eid + (long)n * 16);
    #pragma unroll
    for (int q = 0; q < 4; ++q) {
      int4 t = pa[q];
      ia[q * 4] = t.x; ia[q * 4 + 1] = t.y; ia[q * 4 + 2] = t.z; ia[q * 4 + 3] = t.w;
      int4 u = pe[q];
      ie[q * 4] = u.x; ie[q * 4 + 1] = u.y; ie[q * 4 + 2] = u.z; ie[q * 4 + 3] = u.w;
    }
  }

  // issue all 32 row loads via asm (forced-resident batch)
  u16x8 va[16], ve[16];
  #pragma unroll
  for (int j = 0; j < 16; ++j) {
    const int a = ia[j] >= 0 ? ia[j] : 0;
    gload16(va[j], &nodes[(long)a * DFEAT + c0]);
  }
  #pragma unroll
  for (int j = 0; j < 16; ++j) {
    const int a = ie[j] >= 0 ? ie[j] : 0;
    gload16(ve[j], &edges[(long)a * DFEAT + c0]);
  }

  float s[8] = {0, 0, 0, 0, 0, 0, 0, 0};
  int cnt = 0;
  WAIT_VM(16);  // first 16 (va) landed; ve still in flight
  #pragma unroll
  for (int j = 0; j < 16; ++j) {
    if (ia[j] >= 0) {
      ++cnt;
      #pragma unroll
      for (int i = 0; i < 8; ++i) s[i] += bf2f(va[j][i]);
    }
  }
  WAIT_VM(0);
  #pragma unroll
  for (int j = 0; j < 16; ++j) {
    if (ie[j] >= 0) {
      ++cnt;
      #pragma unroll
      for (int i = 0; i < 8; ++i) s[i] += bf2f(ve[j][i]);
    }
  }
  const float inv = 1.0f / (float)cnt;
  u16x8 o;
  #pragma unroll
  for (int i = 0; i < 8; ++i) o[i] = f2bf(s[i] * inv);
  *reinterpret_cast<u16x8*>(&dst[(long)n * DFEAT + c0]) = o;
}

// ---------------- fused edge update: Een = relu(Ge + mean(Pf[fdep]) + mean(Pb[bdep])) ----------------
__global__ __launch_bounds__(256, 2) void edge_fuse(
    const unsigned short* __restrict__ Pf, const unsigned short* __restrict__ Pb,
    const unsigned short* __restrict__ Ge,
    const int* __restrict__ fdep, const int* __restrict__ bdep,
    unsigned short* __restrict__ Een) {
  const int wave = threadIdx.x >> 6, lane = threadIdx.x & 63;
  const int e = blockIdx.x * 4 + wave;
  const int c0 = lane * 8;

  int idx[16];
  {
    const int4* pf = reinterpret_cast<const int4*>(fdep + (long)e * 8);
    const int4* pb = reinterpret_cast<const int4*>(bdep + (long)e * 8);
    #pragma unroll
    for (int q = 0; q < 2; ++q) {
      int4 t = pf[q];
      idx[q * 4] = t.x; idx[q * 4 + 1] = t.y; idx[q * 4 + 2] = t.z; idx[q * 4 + 3] = t.w;
      int4 u = pb[q];
      idx[8 + q * 4] = u.x; idx[8 + q * 4 + 1] = u.y; idx[8 + q * 4 + 2] = u.z; idx[8 + q * 4 + 3] = u.w;
    }
  }

  u16x8 gv, v[16];
  gload16(gv, &Ge[(long)e * DFEAT + c0]);
  #pragma unroll
  for (int j = 0; j < 8; ++j) {
    const int a = idx[j] >= 0 ? idx[j] : 0;
    gload16(v[j], &Pf[(long)a * DFEAT + c0]);
  }
  #pragma unroll
  for (int j = 0; j < 8; ++j) {
    const int a = idx[8 + j] >= 0 ? idx[8 + j] : 0;
    gload16(v[8 + j], &Pb[(long)a * DFEAT + c0]);
  }
  WAIT_VM(0);

  float sf[8] = {0, 0, 0, 0, 0, 0, 0, 0};
  float sb[8] = {0, 0, 0, 0, 0, 0, 0, 0};
  int fc = 0, bc = 0;
  #pragma unroll
  for (int j = 0; j < 8; ++j) {
    if (idx[j] >= 0) {
      ++fc;
      #pragma unroll
      for (int i = 0; i < 8; ++i) sf[i] += bf2f(v[j][i]);
    }
  }
  #pragma unroll
  for (int j = 0; j < 8; ++j) {
    if (idx[8 + j] >= 0) {
      ++bc;
      #pragma unroll
      for (int i = 0; i < 8; ++i) sb[i] += bf2f(v[8 + j][i]);
    }
  }
  const float invf = 1.0f / (float)fc, invb = 1.0f / (float)bc;
  u16x8 o;
  #pragma unroll
  for (int i = 0; i < 8; ++i) {
    float x = bf2f(gv[i]) + sf[i] * invf + sb[i] * invb;
    o[i] = f2bf(fmaxf(x, 0.0f));
  }
  *reinterpret_cast<u16x8*>(&Een[(long)e * DFEAT + c0]) = o;
}

// ---------------- GEMM args ----------------
struct GArg {
  const unsigned short* A0;
  const unsigned short* A1;
  const unsigned short* Bt;
  const float* bias;
  unsigned short* outb;
  float* outf;
};

// ---------------- node GEMM: C = concat(A0,A1) @ Bt^T + bias, K=1024 ----------------
template<int K, int LDB, int NSEG, int SWZQ, bool RELU, bool BIAS, bool BF16OUT>
__global__ __launch_bounds__(256, 2) void gemm2(GArg ga, GArg gb) {
  const GArg g = blockIdx.z ? gb : ga;
  __shared__ unsigned short As[128][32];
  __shared__ unsigned short Bs[128][32];
  const int tid = threadIdx.x;
  const int wave = tid >> 6, lane = tid & 63;
  const int bid = blockIdx.x;
  const int swz = (bid & 7) * SWZQ + (bid >> 3);
  const long brow = (long)(swz >> 2) * 128;
  const int bcol = (swz & 3) * 128;
  const int wr = (wave >> 1) * 64, wc = (wave & 1) * 64;

  f32x4 acc[4][4] = {};

  const int srow = lane >> 2;
  const int scol = (lane & 3) * 8;
  const int rb = wave * 32;
  unsigned short* As0 = &As[rb][0];
  unsigned short* As1 = &As[rb + 16][0];
  unsigned short* Bs0 = &Bs[rb][0];
  unsigned short* Bs1 = &Bs[rb + 16][0];

  const int fr = lane & 15;
  const int fk = (lane >> 4) * 8;

  for (int kt = 0; kt < K / 32; ++kt) {
    const unsigned short* Aseg;
    int kcol;
    if (NSEG == 1) { Aseg = g.A0; kcol = kt * 32; }
    else           { Aseg = (kt < 16) ? g.A0 : g.A1; kcol = (kt & 15) * 32; }
    GLDS16(Aseg + (brow + rb + srow) * DFEAT + kcol + scol, As0);
    GLDS16(Aseg + (brow + rb + 16 + srow) * DFEAT + kcol + scol, As1);
    const long bk = (long)kt * 32;
    GLDS16(g.Bt + (long)(bcol + rb + srow) * LDB + bk + scol, Bs0);
    GLDS16(g.Bt + (long)(bcol + rb + 16 + srow) * LDB + bk + scol, Bs1);
    __syncthreads();
    bf16x8 af[4], bfr[4];
    #pragma unroll
    for (int m = 0; m < 4; ++m) af[m] = *reinterpret_cast<const bf16x8*>(&As[wr + m * 16 + fr][fk]);
    #pragma unroll
    for (int n = 0; n < 4; ++n) bfr[n] = *reinterpret_cast<const bf16x8*>(&Bs[wc + n * 16 + fr][fk]);
    #pragma unroll
    for (int m = 0; m < 4; ++m)
      #pragma unroll
      for (int n = 0; n < 4; ++n)
        acc[m][n] = __builtin_amdgcn_mfma_f32_16x16x32_bf16(af[m], bfr[n], acc[m][n], 0, 0, 0);
    __syncthreads();
  }

  #pragma unroll
  for (int n = 0; n < 4; ++n) {
    const int col = bcol + wc + n * 16 + fr;
    float bv = 0.0f;
    if (BIAS) bv = g.bias[col];
    #pragma unroll
    for (int m = 0; m < 4; ++m) {
      const long row0 = brow + wr + m * 16 + (lane >> 4) * 4;
      #pragma unroll
      for (int i = 0; i < 4; ++i) {
        float v = acc[m][n][i] + bv;
        if (RELU) v = fmaxf(v, 0.0f);
        if (BF16OUT) g.outb[(row0 + i) * DFEAT + col] = f2bf(v);
        else         g.outf[(row0 + i) * DFEAT + col] = v;
      }
    }
  }
}

// ---------------- merged K=512 GEMM dispatch: Pf | Pb | Ge in one grid ----------------
// ranges (post-swizzle): [0,256) Pf, [256,512) Pb, [512,1536) Ge. All LDB=1536.
__global__ __launch_bounds__(256, 2) void gemm3(GArg ga, GArg gb, GArg gc) {
  __shared__ unsigned short As[128][32];
  __shared__ unsigned short Bs[128][32];
  const int tid = threadIdx.x;
  const int wave = tid >> 6, lane = tid & 63;
  const int bid = blockIdx.x;                      // 1536 blocks
  const int swz = (bid & 7) * 192 + (bid >> 3);    // m204 bijective XCD swizzle
  GArg g; int base;
  if (swz < 256)      { g = ga; base = swz; }
  else if (swz < 512) { g = gb; base = swz - 256; }
  else                { g = gc; base = swz - 512; }
  const long brow = (long)(base >> 2) * 128;
  const int bcol = (base & 3) * 128;
  const int wr = (wave >> 1) * 64, wc = (wave & 1) * 64;

  f32x4 acc[4][4] = {};

  const int srow = lane >> 2;
  const int scol = (lane & 3) * 8;
  const int rb = wave * 32;
  unsigned short* As0 = &As[rb][0];
  unsigned short* As1 = &As[rb + 16][0];
  unsigned short* Bs0 = &Bs[rb][0];
  unsigned short* Bs1 = &Bs[rb + 16][0];

  const int fr = lane & 15;
  const int fk = (lane >> 4) * 8;

  for (int kt = 0; kt < 16; ++kt) {                // K=512
    const int kcol = kt * 32;
    GLDS16(g.A0 + (brow + rb + srow) * DFEAT + kcol + scol, As0);
    GLDS16(g.A0 + (brow + rb + 16 + srow) * DFEAT + kcol + scol, As1);
    GLDS16(g.Bt + (long)(bcol + rb + srow) * 1536 + kcol + scol, Bs0);
    GLDS16(g.Bt + (long)(bcol + rb + 16 + srow) * 1536 + kcol + scol, Bs1);
    __syncthreads();
    bf16x8 af[4], bfr[4];
    #pragma unroll
    for (int m = 0; m < 4; ++m) af[m] = *reinterpret_cast<const bf16x8*>(&As[wr + m * 16 + fr][fk]);
    #pragma unroll
    for (int n = 0; n < 4; ++n) bfr[n] = *reinterpret_cast<const bf16x8*>(&Bs[wc + n * 16 + fr][fk]);
    #pragma unroll
    for (int m = 0; m < 4; ++m)
      #pragma unroll
      for (int n = 0; n < 4; ++n)
        acc[m][n] = __builtin_amdgcn_mfma_f32_16x16x32_bf16(af[m], bfr[n], acc[m][n], 0, 0, 0);
    __syncthreads();
  }

  #pragma unroll
  for (int n = 0; n < 4; ++n) {
    const int col = bcol + wc + n * 16 + fr;
    const float bv = g.bias ? g.bias[col] : 0.0f;
    #pragma unroll
    for (int m = 0; m < 4; ++m) {
      const long row0 = brow + wr + m * 16 + (lane >> 4) * 4;
      #pragma unroll
      for (int i = 0; i < 4; ++i)
        g.outb[(row0 + i) * DFEAT + col] = f2bf(acc[m][n][i] + bv);
    }
  }
}

extern "C" void kernel_launch(void* const* d_in, const int* in_sizes, int n_in,
                              void* d_out, int out_size, void* d_ws, size_t ws_size,
                              hipStream_t stream) {
  const float* fw_in   = (const float*)d_in[0];
  const float* bw_in   = (const float*)d_in[1];
  const float* edge_in = (const float*)d_in[2];
  const int* fw_adj    = (const int*)d_in[3];
  const int* bw_adj    = (const int*)d_in[4];
  const int* fw_eid    = (const int*)d_in[5];
  const int* bw_eid    = (const int*)d_in[6];
  const int* fw_dep    = (const int*)d_in[7];
  const int* bw_dep    = (const int*)d_in[8];
  const float* Wfc     = (const float*)d_in[9];
  const float* bfc     = (const float*)d_in[10];
  const float* Wbc     = (const float*)d_in[11];
  const float* bbc     = (const float*)d_in[12];
  const float* Wedge   = (const float*)d_in[13];
  const float* bedge   = (const float*)d_in[14];
  float* out_f = (float*)d_out;

  char* w = (char*)d_ws;
  auto alloc = [&](size_t b) { char* p = w; w += (b + 255) & ~(size_t)255; return p; };
  const size_t nodeB = (size_t)N_NODES * DFEAT * 2;
  const size_t edgeB = (size_t)N_EDGES * DFEAT * 2;
  unsigned short* Ff0 = (unsigned short*)alloc(nodeB);
  unsigned short* Ff1 = (unsigned short*)alloc(nodeB);
  unsigned short* Fb0 = (unsigned short*)alloc(nodeB);
  unsigned short* Fb1 = (unsigned short*)alloc(nodeB);
  unsigned short* Mf  = (unsigned short*)alloc(nodeB);
  unsigned short* Mb  = (unsigned short*)alloc(nodeB);
  unsigned short* Pf  = (unsigned short*)alloc(nodeB);
  unsigned short* Pb  = (unsigned short*)alloc(nodeB);
  unsigned short* Ee0 = (unsigned short*)alloc(edgeB);
  unsigned short* Ee1 = (unsigned short*)alloc(edgeB);
  unsigned short* Ge  = (unsigned short*)alloc(edgeB);
  unsigned short* WfT = (unsigned short*)alloc((size_t)1024 * 512 * 2);
  unsigned short* WbT = (unsigned short*)alloc((size_t)1024 * 512 * 2);
  unsigned short* WeT = (unsigned short*)alloc((size_t)1536 * 512 * 2);
  if ((size_t)(w - (char*)d_ws) > ws_size) return;

  transpose_w3<<<dim3(48, 16, 3), dim3(32, 8), 0, stream>>>(Wfc, Wbc, Wedge, WfT, WbT, WeT);
  {
    const long nn = (long)N_NODES * DFEAT, ne = (long)N_EDGES * DFEAT;
    const long tot = 2 * nn + ne;
    cvt3<<<(int)(tot / 4 / 256), 256, 0, stream>>>(fw_in, bw_in, edge_in, Ff0, Fb0, Ee0, nn, ne);
  }

  unsigned short *Ffc = Ff0, *Ffn = Ff1, *Fbc = Fb0, *Fbn = Fb1, *Eec = Ee0, *Een = Ee1;

  for (int k = 0; k < 3; ++k) {
    nbr_mean2<<<dim3(N_NODES / 4, 2), 256, 0, stream>>>(
        Ffc, Fbc, Eec, fw_adj, bw_adj, fw_eid, bw_eid, Mf, Mb);
    if (k < 2) {
      // node update (fw+bw): Ffn = relu([Ffc|Mf]@Wfc + bfc)
      gemm2<1024, 1024, 2, 32, true, true, true><<<dim3(256, 1, 2), 256, 0, stream>>>(
          GArg{Ffc, Mf, WfT, bfc, Ffn, nullptr}, GArg{Fbc, Mb, WbT, bbc, Fbn, nullptr});
      // merged K=512 dispatch: Pf = Ffn@We2, Pb = Fbn@We3, Ge = Eec@We1 + bedge
      gemm3<<<dim3(1536), 256, 0, stream>>>(
          GArg{Ffn, nullptr, WeT + 512, nullptr, Pf, nullptr},
          GArg{Fbn, nullptr, WeT + 1024, nullptr, Pb, nullptr},
          GArg{Eec, nullptr, WeT, bedge, Ge, nullptr});
      // Een = relu(Ge + mean(Pf[fdep]) + mean(Pb[bdep]))
      edge_fuse<<<N_EDGES / 4, 256, 0, stream>>>(Pf, Pb, Ge, fw_dep, bw_dep, Een);
      unsigned short* t;
      t = Ffc; Ffc = Ffn; Ffn = t;
      t = Fbc; Fbc = Fbn; Fbn = t;
      t = Eec; Eec = Een; Een = t;
    } else {
      gemm2<1024, 1024, 2, 32, false, true, false><<<dim3(256, 1, 2), 256, 0, stream>>>(
          GArg{Ffc, Mf, WfT, bfc, nullptr, out_f},
          GArg{Fbc, Mb, WbT, bbc, nullptr, out_f + (long)N_NODES * DFEAT});
    }
  }
}

// Round 7
// 500.795 us; speedup vs baseline: 1.3048x; 1.0511x over previous
//
#include <hip/hip_runtime.h>
#include <hip/hip_bf16.h>

#define N_NODES 8192
#define N_EDGES 32768
#define DFEAT   512

typedef __attribute__((ext_vector_type(8))) short          bf16x8;
typedef __attribute__((ext_vector_type(4))) float          f32x4;
typedef __attribute__((ext_vector_type(8))) unsigned short u16x8;

__device__ __forceinline__ float bf2f(unsigned short u) {
  union { unsigned int i; float f; } x; x.i = ((unsigned int)u) << 16; return x.f;
}
__device__ __forceinline__ unsigned short f2bf(float f) {
  __hip_bfloat16 h = __float2bfloat16(f);
  return *reinterpret_cast<unsigned short*>(&h);
}

#define GLDS16(gp, lp) __builtin_amdgcn_global_load_lds( \
    (const __attribute__((address_space(1))) void*)(gp),  \
    (__attribute__((address_space(3))) void*)(lp), 16, 0, 0)

// inline-asm 16B gather load: forces the whole batch to stay in flight
__device__ __forceinline__ void gload16(u16x8& d, const unsigned short* p) {
  asm volatile("global_load_dwordx4 %0, %1, off" : "=v"(d) : "v"(p));
}
#define WAIT_VM(N) do { \
  asm volatile("s_waitcnt vmcnt(" #N ")" ::: "memory"); \
  __builtin_amdgcn_sched_barrier(0); \
} while (0)

// ---------------- merged weight transposes fp32[K][512] -> bf16[512][K] ----------------
__global__ void transpose_w3(const float* __restrict__ W0, const float* __restrict__ W1,
                             const float* __restrict__ W2,
                             unsigned short* __restrict__ T0, unsigned short* __restrict__ T1,
                             unsigned short* __restrict__ T2) {
  __shared__ float tile[32][33];
  const float* W; unsigned short* WT; int K;
  if (blockIdx.z == 0)      { W = W0; WT = T0; K = 1024; }
  else if (blockIdx.z == 1) { W = W1; WT = T1; K = 1024; }
  else                      { W = W2; WT = T2; K = 1536; }
  const int k0 = blockIdx.x * 32, n0 = blockIdx.y * 32;
  if (k0 >= K) return;
  const int tx = threadIdx.x, ty = threadIdx.y;
  #pragma unroll
  for (int i = ty; i < 32; i += 8)
    tile[i][tx] = W[(long)(k0 + i) * DFEAT + n0 + tx];
  __syncthreads();
  #pragma unroll
  for (int i = ty; i < 32; i += 8)
    WT[(long)(n0 + i) * K + k0 + tx] = f2bf(tile[tx][i]);
}

// ---------------- merged fp32 -> bf16 convert for fw/bw/edge ----------------
__global__ void cvt3(const float* __restrict__ a, const float* __restrict__ b,
                     const float* __restrict__ c,
                     unsigned short* __restrict__ da, unsigned short* __restrict__ db,
                     unsigned short* __restrict__ dc, long na, long nc) {
  long i = ((long)blockIdx.x * blockDim.x + threadIdx.x) * 4;
  const float* s; unsigned short* d; long off;
  if (i < na)           { s = a; d = da; off = i; }
  else if (i < 2 * na)  { s = b; d = db; off = i - na; }
  else if (i < 2 * na + nc) { s = c; d = dc; off = i - 2 * na; }
  else return;
  float4 v = *reinterpret_cast<const float4*>(&s[off]);
  ushort4 o = { f2bf(v.x), f2bf(v.y), f2bf(v.z), f2bf(v.w) };
  *reinterpret_cast<ushort4*>(&d[off]) = o;
}

// ---------------- GEMM core: 128x128 tile, BK=64, XOR-swizzled LDS ----------------
// LDS layout: physical (row r, u16 col p) holds logical col p ^ ((r&7)*8).
// global_load_lds writes linearly -> source col is pre-swizzled (rule #21).
struct GArg {
  const unsigned short* A0;
  const unsigned short* A1;
  const unsigned short* Bt;
  const float* bias;
  unsigned short* outb;
  float* outf;
};

template<int K, int LDB, int NSEG, bool RELU, bool BIAS, bool BF16OUT>
__device__ __forceinline__ void gemm_core(GArg g, long brow, int bcol,
                                          unsigned short (*As)[64],
                                          unsigned short (*Bs)[64]) {
  const int tid = threadIdx.x;
  const int wave = tid >> 6, lane = tid & 63;
  const int wr = (wave >> 1) * 64, wc = (wave & 1) * 64;
  f32x4 acc[4][4] = {};

  const int rb = wave * 32;           // rows this wave stages
  const int sl8 = lane >> 3;          // 0..7: row within an 8-row chunk
  const int scol = ((lane & 7) ^ sl8) * 8;   // pre-swizzled source col (u16)
  const int fr = lane & 15;
  const int fk = (lane >> 4) * 8;

  for (int kt = 0; kt < K / 64; ++kt) {
    const unsigned short* Aseg; int kcol;
    if (NSEG == 1) { Aseg = g.A0; kcol = kt * 64; }
    else           { Aseg = (kt < 8) ? g.A0 : g.A1; kcol = (kt & 7) * 64; }
    #pragma unroll
    for (int c = 0; c < 4; ++c)
      GLDS16(Aseg + (brow + rb + 8 * c + sl8) * DFEAT + kcol + scol, &As[rb + 8 * c][0]);
    const long bk = (long)kt * 64;
    #pragma unroll
    for (int c = 0; c < 4; ++c)
      GLDS16(g.Bt + (long)(bcol + rb + 8 * c + sl8) * LDB + bk + scol, &Bs[rb + 8 * c][0]);
    __syncthreads();
    #pragma unroll
    for (int kk = 0; kk < 2; ++kk) {
      bf16x8 af[4], bfr[4];
      #pragma unroll
      for (int m = 0; m < 4; ++m) {
        const int R = wr + m * 16 + fr;
        af[m] = *reinterpret_cast<const bf16x8*>(&As[R][(kk * 32 + fk) ^ ((R & 7) * 8)]);
      }
      #pragma unroll
      for (int n = 0; n < 4; ++n) {
        const int R = wc + n * 16 + fr;
        bfr[n] = *reinterpret_cast<const bf16x8*>(&Bs[R][(kk * 32 + fk) ^ ((R & 7) * 8)]);
      }
      #pragma unroll
      for (int m = 0; m < 4; ++m)
        #pragma unroll
        for (int n = 0; n < 4; ++n)
          acc[m][n] = __builtin_amdgcn_mfma_f32_16x16x32_bf16(af[m], bfr[n], acc[m][n], 0, 0, 0);
    }
    __syncthreads();
  }

  // epilogue: C/D layout (verified m89): col = lane&15, row = (lane>>4)*4 + i
  #pragma unroll
  for (int n = 0; n < 4; ++n) {
    const int col = bcol + wc + n * 16 + fr;
    float bv = 0.0f;
    if (BIAS) bv = g.bias[col];
    #pragma unroll
    for (int m = 0; m < 4; ++m) {
      const long row0 = brow + wr + m * 16 + (lane >> 4) * 4;
      #pragma unroll
      for (int i = 0; i < 4; ++i) {
        float v = acc[m][n][i] + bv;
        if (RELU) v = fmaxf(v, 0.0f);
        if (BF16OUT) g.outb[(row0 + i) * DFEAT + col] = f2bf(v);
        else         g.outf[(row0 + i) * DFEAT + col] = v;
      }
    }
  }
}

// ---------------- standalone GEMM kernel (node update / projections) ----------------
template<int K, int LDB, int NSEG, int SWZQ, bool RELU, bool BIAS, bool BF16OUT>
__global__ __launch_bounds__(256, 2) void gemmK(GArg ga, GArg gb) {
  __shared__ unsigned short As[128][64];
  __shared__ unsigned short Bs[128][64];
  const GArg g = blockIdx.z ? gb : ga;
  const int bid = blockIdx.x;
  const int swz = (bid & 7) * SWZQ + (bid >> 3);   // m204 bijective XCD swizzle
  gemm_core<K, LDB, NSEG, RELU, BIAS, BF16OUT>(
      g, (long)(swz >> 2) * 128, (swz & 3) * 128, As, Bs);
}

// ---------------- fused dispatch: nbr-mean gather blocks + Ge GEMM blocks ----------------
// bid%5==4 -> Ge GEMM block (compute-bound), else nbr gather (L2/L3-BW-bound).
// Interleave co-locates both kinds on each CU so MFMA pipe and cache BW overlap.
__global__ __launch_bounds__(256) void fused_nbr_ge(
    const unsigned short* __restrict__ nodesF, const unsigned short* __restrict__ nodesB,
    const unsigned short* __restrict__ edges,
    const int* __restrict__ adjF, const int* __restrict__ adjB,
    const int* __restrict__ eidF, const int* __restrict__ eidB,
    unsigned short* __restrict__ dstF, unsigned short* __restrict__ dstB,
    GArg ge, int hasGe) {
  __shared__ unsigned short As[128][64];
  __shared__ unsigned short Bs[128][64];
  int bid = blockIdx.x;
  if (hasGe) {
    if ((bid % 5) == 4) {
      const int gid = bid / 5;                         // [0,1024)
      const int swz = (gid & 7) * 128 + (gid >> 3);    // XCD swizzle
      gemm_core<512, 1536, 1, false, true, true>(
          ge, (long)(swz >> 2) * 128, (swz & 3) * 128, As, Bs);
      return;
    }
    bid = (bid / 5) * 4 + (bid % 5);                   // [0,4096)
  }
  // ---- nbr path ----
  const int wave = threadIdx.x >> 6, lane = threadIdx.x & 63;
  const int side = bid >> 11;                          // 2048 blocks per side
  const int n = (bid & 2047) * 4 + wave;
  const unsigned short* nodes; const int* adj; const int* eid; unsigned short* dst;
  if (side == 0) { nodes = nodesF; adj = adjF; eid = eidF; dst = dstF; }
  else           { nodes = nodesB; adj = adjB; eid = eidB; dst = dstB; }
  const int c0 = lane * 8;

  int ia[16], ie[16];
  {
    const int4* pa = reinterpret_cast<const int4*>(adj + (long)n * 16);
    const int4* pe = reinterpret_cast<const int4*>(eid + (long)n * 16);
    #pragma unroll
    for (int q = 0; q < 4; ++q) {
      int4 t = pa[q];
      ia[q * 4] = t.x; ia[q * 4 + 1] = t.y; ia[q * 4 + 2] = t.z; ia[q * 4 + 3] = t.w;
      int4 u = pe[q];
      ie[q * 4] = u.x; ie[q * 4 + 1] = u.y; ie[q * 4 + 2] = u.z; ie[q * 4 + 3] = u.w;
    }
  }

  u16x8 va[16], ve[16];
  #pragma unroll
  for (int j = 0; j < 16; ++j) {
    const int a = ia[j] >= 0 ? ia[j] : 0;
    gload16(va[j], &nodes[(long)a * DFEAT + c0]);
  }
  #pragma unroll
  for (int j = 0; j < 16; ++j) {
    const int a = ie[j] >= 0 ? ie[j] : 0;
    gload16(ve[j], &edges[(long)a * DFEAT + c0]);
  }

  float s[8] = {0, 0, 0, 0, 0, 0, 0, 0};
  int cnt = 0;
  WAIT_VM(16);
  #pragma unroll
  for (int j = 0; j < 16; ++j) {
    if (ia[j] >= 0) {
      ++cnt;
      #pragma unroll
      for (int i = 0; i < 8; ++i) s[i] += bf2f(va[j][i]);
    }
  }
  WAIT_VM(0);
  #pragma unroll
  for (int j = 0; j < 16; ++j) {
    if (ie[j] >= 0) {
      ++cnt;
      #pragma unroll
      for (int i = 0; i < 8; ++i) s[i] += bf2f(ve[j][i]);
    }
  }
  const float inv = 1.0f / (float)cnt;
  u16x8 o;
  #pragma unroll
  for (int i = 0; i < 8; ++i) o[i] = f2bf(s[i] * inv);
  *reinterpret_cast<u16x8*>(&dst[(long)n * DFEAT + c0]) = o;
}

// ---------------- fused edge update: Een = relu(Ge + mean(Pf[fdep]) + mean(Pb[bdep])) ----------------
__global__ __launch_bounds__(256, 2) void edge_fuse(
    const unsigned short* __restrict__ Pf, const unsigned short* __restrict__ Pb,
    const unsigned short* __restrict__ Ge,
    const int* __restrict__ fdep, const int* __restrict__ bdep,
    unsigned short* __restrict__ Een) {
  const int wave = threadIdx.x >> 6, lane = threadIdx.x & 63;
  const int e = blockIdx.x * 4 + wave;
  const int c0 = lane * 8;

  int idx[16];
  {
    const int4* pf = reinterpret_cast<const int4*>(fdep + (long)e * 8);
    const int4* pb = reinterpret_cast<const int4*>(bdep + (long)e * 8);
    #pragma unroll
    for (int q = 0; q < 2; ++q) {
      int4 t = pf[q];
      idx[q * 4] = t.x; idx[q * 4 + 1] = t.y; idx[q * 4 + 2] = t.z; idx[q * 4 + 3] = t.w;
      int4 u = pb[q];
      idx[8 + q * 4] = u.x; idx[8 + q * 4 + 1] = u.y; idx[8 + q * 4 + 2] = u.z; idx[8 + q * 4 + 3] = u.w;
    }
  }

  u16x8 gv, v[16];
  gload16(gv, &Ge[(long)e * DFEAT + c0]);
  #pragma unroll
  for (int j = 0; j < 8; ++j) {
    const int a = idx[j] >= 0 ? idx[j] : 0;
    gload16(v[j], &Pf[(long)a * DFEAT + c0]);
  }
  #pragma unroll
  for (int j = 0; j < 8; ++j) {
    const int a = idx[8 + j] >= 0 ? idx[8 + j] : 0;
    gload16(v[8 + j], &Pb[(long)a * DFEAT + c0]);
  }
  WAIT_VM(0);

  float sf[8] = {0, 0, 0, 0, 0, 0, 0, 0};
  float sb[8] = {0, 0, 0, 0, 0, 0, 0, 0};
  int fc = 0, bc = 0;
  #pragma unroll
  for (int j = 0; j < 8; ++j) {
    if (idx[j] >= 0) {
      ++fc;
      #pragma unroll
      for (int i = 0; i < 8; ++i) sf[i] += bf2f(v[j][i]);
    }
  }
  #pragma unroll
  for (int j = 0; j < 8; ++j) {
    if (idx[8 + j] >= 0) {
      ++bc;
      #pragma unroll
      for (int i = 0; i < 8; ++i) sb[i] += bf2f(v[8 + j][i]);
    }
  }
  const float invf = 1.0f / (float)fc, invb = 1.0f / (float)bc;
  u16x8 o;
  #pragma unroll
  for (int i = 0; i < 8; ++i) {
    float x = bf2f(gv[i]) + sf[i] * invf + sb[i] * invb;
    o[i] = f2bf(fmaxf(x, 0.0f));
  }
  *reinterpret_cast<u16x8*>(&Een[(long)e * DFEAT + c0]) = o;
}

extern "C" void kernel_launch(void* const* d_in, const int* in_sizes, int n_in,
                              void* d_out, int out_size, void* d_ws, size_t ws_size,
                              hipStream_t stream) {
  const float* fw_in   = (const float*)d_in[0];
  const float* bw_in   = (const float*)d_in[1];
  const float* edge_in = (const float*)d_in[2];
  const int* fw_adj    = (const int*)d_in[3];
  const int* bw_adj    = (const int*)d_in[4];
  const int* fw_eid    = (const int*)d_in[5];
  const int* bw_eid    = (const int*)d_in[6];
  const int* fw_dep    = (const int*)d_in[7];
  const int* bw_dep    = (const int*)d_in[8];
  const float* Wfc     = (const float*)d_in[9];
  const float* bfc     = (const float*)d_in[10];
  const float* Wbc     = (const float*)d_in[11];
  const float* bbc     = (const float*)d_in[12];
  const float* Wedge   = (const float*)d_in[13];
  const float* bedge   = (const float*)d_in[14];
  float* out_f = (float*)d_out;

  char* w = (char*)d_ws;
  auto alloc = [&](size_t b) { char* p = w; w += (b + 255) & ~(size_t)255; return p; };
  const size_t nodeB = (size_t)N_NODES * DFEAT * 2;
  const size_t edgeB = (size_t)N_EDGES * DFEAT * 2;
  unsigned short* Ff0 = (unsigned short*)alloc(nodeB);
  unsigned short* Ff1 = (unsigned short*)alloc(nodeB);
  unsigned short* Fb0 = (unsigned short*)alloc(nodeB);
  unsigned short* Fb1 = (unsigned short*)alloc(nodeB);
  unsigned short* Mf  = (unsigned short*)alloc(nodeB);
  unsigned short* Mb  = (unsigned short*)alloc(nodeB);
  unsigned short* Pf  = (unsigned short*)alloc(nodeB);
  unsigned short* Pb  = (unsigned short*)alloc(nodeB);
  unsigned short* Ee0 = (unsigned short*)alloc(edgeB);
  unsigned short* Ee1 = (unsigned short*)alloc(edgeB);
  unsigned short* Ge  = (unsigned short*)alloc(edgeB);
  unsigned short* WfT = (unsigned short*)alloc((size_t)1024 * 512 * 2);
  unsigned short* WbT = (unsigned short*)alloc((size_t)1024 * 512 * 2);
  unsigned short* WeT = (unsigned short*)alloc((size_t)1536 * 512 * 2);
  if ((size_t)(w - (char*)d_ws) > ws_size) return;

  transpose_w3<<<dim3(48, 16, 3), dim3(32, 8), 0, stream>>>(Wfc, Wbc, Wedge, WfT, WbT, WeT);
  {
    const long nn = (long)N_NODES * DFEAT, ne = (long)N_EDGES * DFEAT;
    const long tot = 2 * nn + ne;
    cvt3<<<(int)(tot / 4 / 256), 256, 0, stream>>>(fw_in, bw_in, edge_in, Ff0, Fb0, Ee0, nn, ne);
  }

  unsigned short *Ffc = Ff0, *Ffn = Ff1, *Fbc = Fb0, *Fbn = Fb1, *Eec = Ee0, *Een = Ee1;

  for (int k = 0; k < 3; ++k) {
    const int hasGe = (k < 2) ? 1 : 0;
    // nbr-mean gathers (+ concurrent Ge = Eec@We1 + bedge blocks when k<2)
    fused_nbr_ge<<<hasGe ? 5120 : 4096, 256, 0, stream>>>(
        Ffc, Fbc, Eec, fw_adj, bw_adj, fw_eid, bw_eid, Mf, Mb,
        GArg{Eec, nullptr, WeT, bedge, Ge, nullptr}, hasGe);
    if (k < 2) {
      // node update (fw+bw): Ffn = relu([Ffc|Mf]@Wfc + bfc)
      gemmK<1024, 1024, 2, 32, true, true, true><<<dim3(256, 1, 2), 256, 0, stream>>>(
          GArg{Ffc, Mf, WfT, bfc, Ffn, nullptr}, GArg{Fbc, Mb, WbT, bbc, Fbn, nullptr});
      // projections: Pf = Ffn@We2, Pb = Fbn@We3
      gemmK<512, 1536, 1, 32, false, false, true><<<dim3(256, 1, 2), 256, 0, stream>>>(
          GArg{Ffn, nullptr, WeT + 512, nullptr, Pf, nullptr},
          GArg{Fbn, nullptr, WeT + 1024, nullptr, Pb, nullptr});
      // Een = relu(Ge + mean(Pf[fdep]) + mean(Pb[bdep]))
      edge_fuse<<<N_EDGES / 4, 256, 0, stream>>>(Pf, Pb, Ge, fw_dep, bw_dep, Een);
      unsigned short* t;
      t = Ffc; Ffc = Ffn; Ffn = t;
      t = Fbc; Fbc = Fbn; Fbn = t;
      t = Eec; Eec = Een; Een = t;
    } else {
      gemmK<1024, 1024, 2, 32, false, true, false><<<dim3(256, 1, 2), 256, 0, stream>>>(
          GArg{Ffc, Mf, WfT, bfc, nullptr, out_f},
          GArg{Fbc, Mb, WbT, bbc, nullptr, out_f + (long)N_NODES * DFEAT});
    }
  }
}